// Round 6
// baseline (338.208 us; speedup 1.0000x reference)
//
#include <hip/hip_runtime.h>
#include <hip/hip_bf16.h>
#include <math.h>

#define DIM      1024
#define D_STATE  64
#define D_CONV   4
#define N_HEADS  8
#define D_INNER  2048
#define HEAD_DIM 256
#define NPROJ    4232      // 2048 + 2048 + 8 + 64 + 64
#define BATCH    2
#define SEQ      1024
#define M_ROWS   (BATCH * SEQ)   // 2048
#define OFF_Z    0
#define OFF_XC   2048
#define OFF_DT   4096
#define OFF_B    4104
#define OFF_C    4168

#define CHUNK    64
#define N_CHUNK  (SEQ / CHUNK)    // 16
#define STATE_PER_BH (HEAD_DIM * D_STATE)   // 16384 floats

#define NPROJ_PAD 4352            // 34 * 128 (GEMM1 N padded to tile)

typedef unsigned short u16;
typedef __bf16 bf16x8 __attribute__((ext_vector_type(8)));
typedef float  f32x4  __attribute__((ext_vector_type(4)));

__device__ __forceinline__ u16 f2bf(float f) {
    unsigned int u = __float_as_uint(f);
    unsigned int r = (u + 0x7FFFu + ((u >> 16) & 1u)) >> 16;   // RNE
    return (u16)r;
}
__device__ __forceinline__ float bf2f(u16 h) {
    return __uint_as_float(((unsigned int)h) << 16);
}

__device__ __forceinline__ void load_lds16(const void* g, void* l) {
    __builtin_amdgcn_global_load_lds((const __attribute__((address_space(1))) unsigned int*)g,
                                     (__attribute__((address_space(3))) unsigned int*)l,
                                     16, 0, 0);
}

// ---------------------------------------------------------------------------
// merged split-cast for two segments (x and in_proj_w), zero tail padding.
// ---------------------------------------------------------------------------
__global__ __launch_bounds__(256) void cast_split2_kernel(
        const float* __restrict__ s0, u16* __restrict__ h0, u16* __restrict__ l0, int n0,
        const float* __restrict__ s1, u16* __restrict__ h1, u16* __restrict__ l1,
        int n1_src, int n1_tot) {
    int i4 = (blockIdx.x * 256 + threadIdx.x) * 4;
    const float* src; u16 *hi, *lo; int nsrc;
    if (i4 < n0) {
        src = s0; hi = h0; lo = l0; nsrc = n0;
    } else {
        i4 -= n0;
        if (i4 >= n1_tot) return;
        src = s1; hi = h1; lo = l1; nsrc = n1_src;
    }
    ushort4 h, l;
    if (i4 < nsrc) {
        float4 v = *(const float4*)&src[i4];
        h.x = f2bf(v.x); h.y = f2bf(v.y); h.z = f2bf(v.z); h.w = f2bf(v.w);
        l.x = f2bf(v.x - bf2f(h.x));
        l.y = f2bf(v.y - bf2f(h.y));
        l.z = f2bf(v.z - bf2f(h.z));
        l.w = f2bf(v.w - bf2f(h.w));
    } else {
        h.x = h.y = h.z = h.w = 0;
        l.x = l.y = l.z = l.w = 0;
    }
    *(ushort4*)&hi[i4] = h;
    *(ushort4*)&lo[i4] = l;
}

__global__ __launch_bounds__(256) void cast_split_kernel(const float* __restrict__ src,
                                                         u16* __restrict__ hi,
                                                         u16* __restrict__ lo, int n) {
    int i4 = (blockIdx.x * 256 + threadIdx.x) * 4;
    if (i4 >= n) return;
    float4 v = *(const float4*)&src[i4];
    ushort4 h, l;
    h.x = f2bf(v.x); h.y = f2bf(v.y); h.z = f2bf(v.z); h.w = f2bf(v.w);
    l.x = f2bf(v.x - bf2f(h.x));
    l.y = f2bf(v.y - bf2f(h.y));
    l.z = f2bf(v.z - bf2f(h.z));
    l.w = f2bf(v.w - bf2f(h.w));
    *(ushort4*)&hi[i4] = h;
    *(ushort4*)&lo[i4] = l;
}

// ---------------------------------------------------------------------------
// split-bf16 MFMA GEMM: C = A @ B^T, A ~ Ah+Al, B ~ Bh+Bl, fp32 accum.
// acc += Ah*Bh + Al*Bh + Ah*Bl.  BM=128 x BN tile, BK=32, 256 thr (2x2 waves).
// Optional split-K via gridDim.z; slice z writes C + z*zstride.
// ---------------------------------------------------------------------------
template<int BN>
__global__ __launch_bounds__(256) void gemm_mfma3(const u16* __restrict__ Ah,
                                                  const u16* __restrict__ Al,
                                                  const u16* __restrict__ Bh,
                                                  const u16* __restrict__ Bl,
                                                  float* __restrict__ C,
                                                  int K, int ldc, int Nstore,
                                                  size_t zstride) {
    __shared__ u16 AsH[128 * 32];
    __shared__ u16 AsL[128 * 32];
    __shared__ u16 BsH[BN * 32];
    __shared__ u16 BsL[BN * 32];

    const int tid  = threadIdx.x;
    const int wave = tid >> 6;
    const int lane = tid & 63;
    const int fr   = lane & 15;
    const int kc   = lane >> 4;
    const int m0   = blockIdx.y * 128;
    const int n0   = blockIdx.x * BN;
    const int wm   = (wave & 1) * 64;
    const int wn   = (wave >> 1) * (BN / 2);

    const int kPer = K / gridDim.z;
    const int kBeg = blockIdx.z * kPer;
    C += (size_t)blockIdx.z * zstride;

    f32x4 acc[4][BN / 32];
#pragma unroll
    for (int i = 0; i < 4; ++i)
#pragma unroll
        for (int j = 0; j < BN / 32; ++j) acc[i][j] = (f32x4)0.f;

    for (int k0 = kBeg; k0 < kBeg + kPer; k0 += 32) {
        __syncthreads();
#pragma unroll
        for (int q = 0; q < 2; ++q) {
            int s = wave * 128 + q * 64 + lane;
            int r = s >> 2, pc = s & 3;
            int gc = pc ^ ((r >> 1) & 3);
            size_t goff = (size_t)(m0 + r) * K + k0 + gc * 8;
            load_lds16(Ah + goff, &AsH[(wave * 128 + q * 64) * 8]);
            load_lds16(Al + goff, &AsL[(wave * 128 + q * 64) * 8]);
        }
#pragma unroll
        for (int q = 0; q < BN / 64; ++q) {
            int s = wave * BN + q * 64 + lane;
            int r = s >> 2, pc = s & 3;
            int gc = pc ^ ((r >> 1) & 3);
            size_t goff = (size_t)(n0 + r) * K + k0 + gc * 8;
            load_lds16(Bh + goff, &BsH[(wave * BN + q * 64) * 8]);
            load_lds16(Bl + goff, &BsL[(wave * BN + q * 64) * 8]);
        }
        __syncthreads();

        bf16x8 afh[4], afl[4];
#pragma unroll
        for (int i = 0; i < 4; ++i) {
            int r = wm + i * 16 + fr;
            int off = r * 32 + (kc ^ ((r >> 1) & 3)) * 8;
            afh[i] = *(const bf16x8*)&AsH[off];
            afl[i] = *(const bf16x8*)&AsL[off];
        }
        bf16x8 bfh[BN / 32], bfl[BN / 32];
#pragma unroll
        for (int j = 0; j < BN / 32; ++j) {
            int r = wn + j * 16 + fr;
            int off = r * 32 + (kc ^ ((r >> 1) & 3)) * 8;
            bfh[j] = *(const bf16x8*)&BsH[off];
            bfl[j] = *(const bf16x8*)&BsL[off];
        }
#pragma unroll
        for (int i = 0; i < 4; ++i)
#pragma unroll
            for (int j = 0; j < BN / 32; ++j) {
                acc[i][j] = __builtin_amdgcn_mfma_f32_16x16x32_bf16(afh[i], bfh[j], acc[i][j], 0, 0, 0);
                acc[i][j] = __builtin_amdgcn_mfma_f32_16x16x32_bf16(afl[i], bfh[j], acc[i][j], 0, 0, 0);
                acc[i][j] = __builtin_amdgcn_mfma_f32_16x16x32_bf16(afh[i], bfl[j], acc[i][j], 0, 0, 0);
            }
    }

    // epilogue: C/D layout col=lane&15, row=(lane>>4)*4+reg  [m89/m91]
    const int row0 = m0 + wm + (lane >> 4) * 4;
    const int colb = n0 + wn + fr;
#pragma unroll
    for (int i = 0; i < 4; ++i)
#pragma unroll
        for (int j = 0; j < BN / 32; ++j) {
            int col = colb + j * 16;
            if (col < Nstore) {
#pragma unroll
                for (int t = 0; t < 4; ++t)
                    C[(size_t)(row0 + i * 16 + t) * ldc + col] = acc[i][j][t];
            }
        }
}

// ---------------------------------------------------------------------------
// split-K=4 partial reduce
// ---------------------------------------------------------------------------
__global__ __launch_bounds__(256) void reduce4_kernel(const float* __restrict__ p,
                                                      float* __restrict__ out, int n) {
    int i4 = (blockIdx.x * 256 + threadIdx.x) * 4;
    float4 a = *(const float4*)&p[i4];
    float4 b = *(const float4*)&p[(size_t)n + i4];
    float4 c = *(const float4*)&p[2 * (size_t)n + i4];
    float4 d = *(const float4*)&p[3 * (size_t)n + i4];
    *(float4*)&out[i4] = make_float4(a.x + b.x + c.x + d.x, a.y + b.y + c.y + d.y,
                                     a.z + b.z + c.z + d.z, a.w + b.w + c.w + d.w);
}

// ---------------------------------------------------------------------------
// helpers for fused dt/abar
// ---------------------------------------------------------------------------
__device__ __forceinline__ float softplus_f(float v) {
    return (v > 20.f) ? v : log1pf(expf(v));
}

// ---------------------------------------------------------------------------
// PASS 1: local scan within a 64-step chunk; conv+SiLU and dt/abar computed
// inline from zx; writes yscan = y_local + D*x and the chunk's final state.
// ---------------------------------------------------------------------------
#define SCHUNK 32
__global__ __launch_bounds__(256) void scan_local_kernel(const float* __restrict__ zx,
                                                         const float* __restrict__ conv_w,
                                                         const float* __restrict__ conv_b,
                                                         const float* __restrict__ dt_bias,
                                                         const float* __restrict__ A_log,
                                                         const float* __restrict__ Dp,
                                                         float* __restrict__ yscan,
                                                         float* __restrict__ Sloc) {
    const int blk = blockIdx.x;          // 0..1023
    const int dq = blk & 3;
    const int c  = (blk >> 2) & (N_CHUNK - 1);
    const int bh = blk >> 6;
    const int hh = bh & (N_HEADS - 1);
    const int b  = bh >> 3;
    const int t  = threadIdx.x;
    const int d_local = t >> 2;
    const int g = t & 3;

    __shared__ float aS[SCHUNK];
    __shared__ float bS[SCHUNK][D_STATE];
    __shared__ float cS[SCHUNK][D_STATE];
    __shared__ float xS[SCHUNK][64];

    float hst[16];
#pragma unroll
    for (int i = 0; i < 16; ++i) hst[i] = 0.f;

    const int m0base = b * SEQ + c * CHUNK;
    const int xcol = hh * HEAD_DIM + dq * 64;
    const float Dh = Dp[hh];
    const float Ah = -expf(A_log[hh]);
    const float dtb = dt_bias[hh];

    for (int st = 0; st < CHUNK / SCHUNK; ++st) {
        const int m0 = m0base + st * SCHUNK;
        __syncthreads();
#pragma unroll
        for (int i = 0; i < 8; ++i) {
            int idx = t + i * 256;
            int r = idx >> 6, n = idx & 63;
            int mrow = m0 + r;
            size_t rowz = (size_t)mrow * NPROJ;
            bS[r][n] = zx[rowz + OFF_B + n];
            cS[r][n] = zx[rowz + OFF_C + n];
            // fused depthwise conv(k=4) + SiLU
            int col = xcol + n;
            int l = mrow & (SEQ - 1);
            float acc = conv_b[col];
#pragma unroll
            for (int k = 0; k < D_CONV; ++k) {
                int lj = l + k - (D_CONV - 1);
                if (lj >= 0)
                    acc = fmaf(zx[(size_t)(mrow + k - (D_CONV - 1)) * NPROJ + OFF_XC + col],
                               conv_w[col * D_CONV + k], acc);
            }
            xS[r][n] = acc / (1.f + expf(-acc));
        }
        if (t < SCHUNK) {
            float v = zx[(size_t)(m0 + t) * NPROJ + OFF_DT + hh] + dtb;
            aS[t] = expf(softplus_f(v) * Ah);
        }
        __syncthreads();

        for (int r = 0; r < SCHUNK; ++r) {
            float a = aS[r];
            float xd = xS[r][d_local];
            const float* bp = &bS[r][g * 16];
            const float* cp = &cS[r][g * 16];
            float acc0 = 0.f, acc1 = 0.f;
#pragma unroll
            for (int i = 0; i < 16; i += 2) {
                hst[i]     = fmaf(a, hst[i],     bp[i]     * xd);
                acc0       = fmaf(hst[i],     cp[i],     acc0);
                hst[i + 1] = fmaf(a, hst[i + 1], bp[i + 1] * xd);
                acc1       = fmaf(hst[i + 1], cp[i + 1], acc1);
            }
            float acc = acc0 + acc1;
            acc += __shfl_xor(acc, 1);
            acc += __shfl_xor(acc, 2);
            if (g == 0)
                yscan[(size_t)(m0 + r) * D_INNER + xcol + d_local] = fmaf(Dh, xd, acc);
        }
    }

    size_t sbase = ((size_t)(bh * N_CHUNK + c) * HEAD_DIM + dq * 64 + d_local) * D_STATE + g * 16;
#pragma unroll
    for (int i = 0; i < 16; i += 4)
        *(float4*)&Sloc[sbase + i] = make_float4(hst[i], hst[i+1], hst[i+2], hst[i+3]);
}

// ---------------------------------------------------------------------------
// PASS 2: inter-chunk recurrence in place on Sloc -> H_init(c).
// chunk decay product = exp(A * sum(dt)) computed from zx.
// ---------------------------------------------------------------------------
__global__ __launch_bounds__(256) void scan_combine_kernel(const float* __restrict__ zx,
                                                           const float* __restrict__ dt_bias,
                                                           const float* __restrict__ A_log,
                                                           float* __restrict__ Sloc) {
    const int blk = blockIdx.x;
    const int ds = blk & 15;
    const int bh = blk >> 4;
    const int hh = bh & (N_HEADS - 1);
    const int b  = bh >> 3;
    const int t  = threadIdx.x;

    __shared__ float PS[N_CHUNK];
    if (t < N_CHUNK) {
        const float Ah = -expf(A_log[hh]);
        const float dtb = dt_bias[hh];
        float sdt = 0.f;
        int mbase = b * SEQ + t * CHUNK;
        for (int j = 0; j < CHUNK; ++j)
            sdt += softplus_f(zx[(size_t)(mbase + j) * NPROJ + OFF_DT + hh] + dtb);
        PS[t] = expf(Ah * sdt);
    }
    __syncthreads();

    float H[4] = {0.f, 0.f, 0.f, 0.f};
    for (int c = 0; c < N_CHUNK; ++c) {
        size_t base = (size_t)(bh * N_CHUNK + c) * STATE_PER_BH + ds * 1024 + t;
        float Sv[4];
#pragma unroll
        for (int i = 0; i < 4; ++i) Sv[i] = Sloc[base + i * 256];
#pragma unroll
        for (int i = 0; i < 4; ++i) Sloc[base + i * 256] = H[i];
        float P = PS[c];
#pragma unroll
        for (int i = 0; i < 4; ++i) H[i] = fmaf(P, H[i], Sv[i]);
    }
}

// ---------------------------------------------------------------------------
// PASS 3: y_t += cumA(t) * (C_t . H_init(chunk)); dt/abar inline from zx.
// ---------------------------------------------------------------------------
__global__ __launch_bounds__(256) void scan_correct_kernel(const float* __restrict__ zx,
                                                           const float* __restrict__ dt_bias,
                                                           const float* __restrict__ A_log,
                                                           const float* __restrict__ Hini,
                                                           float* __restrict__ yscan) {
    const int blk = blockIdx.x;
    const int dq = blk & 3;
    const int c  = (blk >> 2) & (N_CHUNK - 1);
    const int bh = blk >> 6;
    const int hh = bh & (N_HEADS - 1);
    const int b  = bh >> 3;
    const int t  = threadIdx.x;
    const int d_local = t >> 2;
    const int g = t & 3;

    __shared__ float cS[CHUNK][D_STATE];
    __shared__ float aS[CHUNK];

    const int m0 = b * SEQ + c * CHUNK;
#pragma unroll
    for (int i = 0; i < 16; ++i) {
        int idx = t + i * 256;
        int r = idx >> 6, n = idx & 63;
        cS[r][n] = zx[(size_t)(m0 + r) * NPROJ + OFF_C + n];
    }
    if (t < CHUNK) {
        float v = zx[(size_t)(m0 + t) * NPROJ + OFF_DT + hh] + dt_bias[hh];
        aS[t] = expf(softplus_f(v) * -expf(A_log[hh]));
    }

    float H[16];
    size_t hbase = ((size_t)(bh * N_CHUNK + c) * HEAD_DIM + dq * 64 + d_local) * D_STATE + g * 16;
#pragma unroll
    for (int i = 0; i < 16; i += 4) {
        float4 v = *(const float4*)&Hini[hbase + i];
        H[i] = v.x; H[i+1] = v.y; H[i+2] = v.z; H[i+3] = v.w;
    }
    __syncthreads();

    const int xcol = hh * HEAD_DIM + dq * 64;
    float cum = 1.f;
    for (int r = 0; r < CHUNK; ++r) {
        cum *= aS[r];
        const float* cp = &cS[r][g * 16];
        float acc0 = 0.f, acc1 = 0.f;
#pragma unroll
        for (int i = 0; i < 16; i += 2) {
            acc0 = fmaf(H[i],     cp[i],     acc0);
            acc1 = fmaf(H[i + 1], cp[i + 1], acc1);
        }
        float acc = acc0 + acc1;
        acc += __shfl_xor(acc, 1);
        acc += __shfl_xor(acc, 2);
        if (g == 0)
            yscan[(size_t)(m0 + r) * D_INNER + xcol + d_local] += cum * acc;
    }
}

// ---------------------------------------------------------------------------
// y = yscan * silu(z); RMSNorm over D_INNER; emits bf16 hi/lo split.
// (D*x already folded into yscan by scan pass 1)
// ---------------------------------------------------------------------------
__global__ __launch_bounds__(256) void gate_norm_kernel(const float* __restrict__ zx,
                                                        const float* __restrict__ nw,
                                                        const float* __restrict__ y,
                                                        u16* __restrict__ ybf_h,
                                                        u16* __restrict__ ybf_l) {
    const int m = blockIdx.x;
    const int t = threadIdx.x;
    const size_t rowz = (size_t)m * NPROJ;
    const size_t rowy = (size_t)m * D_INNER;

    float v[8];
    float ss = 0.f;
#pragma unroll
    for (int i = 0; i < 8; ++i) {
        int c = t + i * 256;
        float ys = y[rowy + c];
        float z  = zx[rowz + OFF_Z + c];
        float gated = ys * (z / (1.f + expf(-z)));
        v[i] = gated;
        ss += gated * gated;
    }
#pragma unroll
    for (int off = 1; off < 64; off <<= 1) ss += __shfl_xor(ss, off);

    __shared__ float red[4];
    if ((t & 63) == 0) red[t >> 6] = ss;
    __syncthreads();
    float tot = red[0] + red[1] + red[2] + red[3];
    float scale = 1.f / sqrtf(tot / (float)D_INNER + 1e-6f);

#pragma unroll
    for (int i = 0; i < 8; ++i) {
        int c = t + i * 256;
        float o = v[i] * scale * nw[c];
        u16 h = f2bf(o);
        ybf_h[rowy + c] = h;
        ybf_l[rowy + c] = f2bf(o - bf2f(h));
    }
}

// ---------------------------------------------------------------------------
extern "C" void kernel_launch(void* const* d_in, const int* in_sizes, int n_in,
                              void* d_out, int out_size, void* d_ws, size_t ws_size,
                              hipStream_t stream) {
    const float* x         = (const float*)d_in[0];
    const float* in_proj_w = (const float*)d_in[1];
    const float* conv_w    = (const float*)d_in[2];
    const float* conv_b    = (const float*)d_in[3];
    const float* A_log     = (const float*)d_in[4];
    const float* D_param   = (const float*)d_in[5];
    const float* dt_bias   = (const float*)d_in[6];
    const float* norm_w    = (const float*)d_in[7];
    const float* out_proj_w= (const float*)d_in[8];
    float* out = (float*)d_out;

    float* ws   = (float*)d_ws;
    float* zx   = ws;                                   // M_ROWS * NPROJ fp32   (34.7 MB)
    float* xr   = zx  + (size_t)M_ROWS * NPROJ;         // M_ROWS * D_INNER fp32 (16.8 MB) — wibf/wobf home
    float* ysc  = xr  + (size_t)M_ROWS * D_INNER;       // M_ROWS * D_INNER fp32 (16.8 MB)
    float* Sloc = ysc + (size_t)M_ROWS * D_INNER;       // 4.19M fp32 (16.8 MB)

    // bf16 hi/lo overlays on regions DEAD at time of use (launch order below):
    u16* xbf_h  = (u16*)ysc;                            // ysc dead until scan pass1
    u16* xbf_l  = xbf_h + (size_t)M_ROWS * DIM;
    u16* wibf_h = (u16*)xr;                             // xr unused until wobf
    u16* wibf_l = (u16*)Sloc;                           // Sloc dead until scan pass1
    u16* ybf_h  = (u16*)Sloc;                           // Sloc dead after scan pass3
    u16* ybf_l  = ybf_h + (size_t)M_ROWS * D_INNER;
    u16* wobf_h = (u16*)xr;                             // wibf dead after GEMM1
    u16* wobf_l = wobf_h + (size_t)DIM * D_INNER;
    float* pbuf = zx;                                   // zx dead after gate_norm (33.6 <= 34.7 MB)

    // merged split casts for GEMM1 (x + padded in_proj_w)
    {
        int n0 = M_ROWS * DIM;                          // 2.10M
        int n1t = NPROJ_PAD * DIM;                      // 4.46M
        cast_split2_kernel<<<(n0 + n1t) / 1024, 256, 0, stream>>>(
            x, xbf_h, xbf_l, n0,
            in_proj_w, wibf_h, wibf_l, NPROJ * DIM, n1t);
    }

    // 1) zxBCdt = x @ in_proj_w^T  (2048 x 4232, K=1024), split bf16 MFMA
    gemm_mfma3<128><<<dim3(NPROJ_PAD / 128, M_ROWS / 128, 1), 256, 0, stream>>>(
        xbf_h, xbf_l, wibf_h, wibf_l, zx, DIM, NPROJ, NPROJ, 0);

    // 2) chunk-parallel scan (conv/silu/dt/abar/D*x fused in)
    scan_local_kernel<<<BATCH * N_HEADS * N_CHUNK * 4, 256, 0, stream>>>(
        zx, conv_w, conv_b, dt_bias, A_log, D_param, ysc, Sloc);
    scan_combine_kernel<<<BATCH * N_HEADS * 16, 256, 0, stream>>>(
        zx, dt_bias, A_log, Sloc);
    scan_correct_kernel<<<BATCH * N_HEADS * N_CHUNK * 4, 256, 0, stream>>>(
        zx, dt_bias, A_log, Sloc, ysc);

    // 3) gate + rmsnorm, emits split-bf16 y
    gate_norm_kernel<<<M_ROWS, 256, 0, stream>>>(zx, norm_w, ysc, ybf_h, ybf_l);

    // 4) split cast for GEMM2 weights
    cast_split_kernel<<<(DIM * D_INNER) / 1024, 256, 0, stream>>>(
        out_proj_w, wobf_h, wobf_l, DIM * D_INNER);

    // 5) out = y @ out_proj_w^T  (2048 x 1024, K=2048), split-K=4 -> pbuf
    gemm_mfma3<128><<<dim3(DIM / 128, M_ROWS / 128, 4), 256, 0, stream>>>(
        ybf_h, ybf_l, wobf_h, wobf_l, pbuf, D_INNER, DIM, DIM,
        (size_t)M_ROWS * DIM);

    // 6) reduce partials -> out
    reduce4_kernel<<<(M_ROWS * DIM) / 1024, 256, 0, stream>>>(pbuf, out, M_ROWS * DIM);
}

// Round 7
// 308.063 us; speedup vs baseline: 1.0979x; 1.0979x over previous
//
#include <hip/hip_runtime.h>
#include <hip/hip_bf16.h>
#include <math.h>

#define DIM      1024
#define D_STATE  64
#define D_CONV   4
#define N_HEADS  8
#define D_INNER  2048
#define HEAD_DIM 256
#define NPROJ    4232      // 2048 + 2048 + 8 + 64 + 64
#define BATCH    2
#define SEQ      1024
#define M_ROWS   (BATCH * SEQ)   // 2048
#define OFF_Z    0
#define OFF_XC   2048
#define OFF_DT   4096
#define OFF_B    4104
#define OFF_C    4168

#define CHUNK    64
#define N_CHUNK  (SEQ / CHUNK)    // 16
#define STATE_PER_BH (HEAD_DIM * D_STATE)   // 16384 floats

#define NPROJ_PAD 4352            // 34 * 128 (GEMM1 N padded to tile)

typedef unsigned short u16;
typedef __bf16 bf16x8 __attribute__((ext_vector_type(8)));
typedef float  f32x4  __attribute__((ext_vector_type(4)));

__device__ __forceinline__ u16 f2bf(float f) {
    unsigned int u = __float_as_uint(f);
    unsigned int r = (u + 0x7FFFu + ((u >> 16) & 1u)) >> 16;   // RNE
    return (u16)r;
}
__device__ __forceinline__ float bf2f(u16 h) {
    return __uint_as_float(((unsigned int)h) << 16);
}

__device__ __forceinline__ void load_lds16(const void* g, void* l) {
    __builtin_amdgcn_global_load_lds((const __attribute__((address_space(1))) unsigned int*)g,
                                     (__attribute__((address_space(3))) unsigned int*)l,
                                     16, 0, 0);
}

__device__ __forceinline__ float softplus_f(float v) {
    return (v > 20.f) ? v : log1pf(expf(v));
}

// ---------------------------------------------------------------------------
// merged split-cast for two segments (x and in_proj_w), zero tail padding.
// ---------------------------------------------------------------------------
__global__ __launch_bounds__(256) void cast_split2_kernel(
        const float* __restrict__ s0, u16* __restrict__ h0, u16* __restrict__ l0, int n0,
        const float* __restrict__ s1, u16* __restrict__ h1, u16* __restrict__ l1,
        int n1_src, int n1_tot) {
    int i4 = (blockIdx.x * 256 + threadIdx.x) * 4;
    const float* src; u16 *hi, *lo; int nsrc;
    if (i4 < n0) {
        src = s0; hi = h0; lo = l0; nsrc = n0;
    } else {
        i4 -= n0;
        if (i4 >= n1_tot) return;
        src = s1; hi = h1; lo = l1; nsrc = n1_src;
    }
    ushort4 h, l;
    if (i4 < nsrc) {
        float4 v = *(const float4*)&src[i4];
        h.x = f2bf(v.x); h.y = f2bf(v.y); h.z = f2bf(v.z); h.w = f2bf(v.w);
        l.x = f2bf(v.x - bf2f(h.x));
        l.y = f2bf(v.y - bf2f(h.y));
        l.z = f2bf(v.z - bf2f(h.z));
        l.w = f2bf(v.w - bf2f(h.w));
    } else {
        h.x = h.y = h.z = h.w = 0;
        l.x = l.y = l.z = l.w = 0;
    }
    *(ushort4*)&hi[i4] = h;
    *(ushort4*)&lo[i4] = l;
}

__global__ __launch_bounds__(256) void cast_split_kernel(const float* __restrict__ src,
                                                         u16* __restrict__ hi,
                                                         u16* __restrict__ lo, int n) {
    int i4 = (blockIdx.x * 256 + threadIdx.x) * 4;
    if (i4 >= n) return;
    float4 v = *(const float4*)&src[i4];
    ushort4 h, l;
    h.x = f2bf(v.x); h.y = f2bf(v.y); h.z = f2bf(v.z); h.w = f2bf(v.w);
    l.x = f2bf(v.x - bf2f(h.x));
    l.y = f2bf(v.y - bf2f(h.y));
    l.z = f2bf(v.z - bf2f(h.z));
    l.w = f2bf(v.w - bf2f(h.w));
    *(ushort4*)&hi[i4] = h;
    *(ushort4*)&lo[i4] = l;
}

// ---------------------------------------------------------------------------
// split-bf16 MFMA GEMM: C = A @ B^T, A ~ Ah+Al, B ~ Bh+Bl, fp32 accum.
// acc += Ah*Bh + Al*Bh + Ah*Bl.  BM=128 x BN tile, BK=32, 256 thr (2x2 waves).
// Optional split-K via gridDim.z; slice z writes C + z*zstride.
// ---------------------------------------------------------------------------
template<int BN>
__global__ __launch_bounds__(256) void gemm_mfma3(const u16* __restrict__ Ah,
                                                  const u16* __restrict__ Al,
                                                  const u16* __restrict__ Bh,
                                                  const u16* __restrict__ Bl,
                                                  float* __restrict__ C,
                                                  int K, int ldc, int Nstore,
                                                  size_t zstride) {
    __shared__ u16 AsH[128 * 32];
    __shared__ u16 AsL[128 * 32];
    __shared__ u16 BsH[BN * 32];
    __shared__ u16 BsL[BN * 32];

    const int tid  = threadIdx.x;
    const int wave = tid >> 6;
    const int lane = tid & 63;
    const int fr   = lane & 15;
    const int kc   = lane >> 4;
    const int m0   = blockIdx.y * 128;
    const int n0   = blockIdx.x * BN;
    const int wm   = (wave & 1) * 64;
    const int wn   = (wave >> 1) * (BN / 2);

    const int kPer = K / gridDim.z;
    const int kBeg = blockIdx.z * kPer;
    C += (size_t)blockIdx.z * zstride;

    f32x4 acc[4][BN / 32];
#pragma unroll
    for (int i = 0; i < 4; ++i)
#pragma unroll
        for (int j = 0; j < BN / 32; ++j) acc[i][j] = (f32x4)0.f;

    for (int k0 = kBeg; k0 < kBeg + kPer; k0 += 32) {
        __syncthreads();
#pragma unroll
        for (int q = 0; q < 2; ++q) {
            int s = wave * 128 + q * 64 + lane;
            int r = s >> 2, pc = s & 3;
            int gc = pc ^ ((r >> 1) & 3);
            size_t goff = (size_t)(m0 + r) * K + k0 + gc * 8;
            load_lds16(Ah + goff, &AsH[(wave * 128 + q * 64) * 8]);
            load_lds16(Al + goff, &AsL[(wave * 128 + q * 64) * 8]);
        }
#pragma unroll
        for (int q = 0; q < BN / 64; ++q) {
            int s = wave * BN + q * 64 + lane;
            int r = s >> 2, pc = s & 3;
            int gc = pc ^ ((r >> 1) & 3);
            size_t goff = (size_t)(n0 + r) * K + k0 + gc * 8;
            load_lds16(Bh + goff, &BsH[(wave * BN + q * 64) * 8]);
            load_lds16(Bl + goff, &BsL[(wave * BN + q * 64) * 8]);
        }
        __syncthreads();

        bf16x8 afh[4], afl[4];
#pragma unroll
        for (int i = 0; i < 4; ++i) {
            int r = wm + i * 16 + fr;
            int off = r * 32 + (kc ^ ((r >> 1) & 3)) * 8;
            afh[i] = *(const bf16x8*)&AsH[off];
            afl[i] = *(const bf16x8*)&AsL[off];
        }
        bf16x8 bfh[BN / 32], bfl[BN / 32];
#pragma unroll
        for (int j = 0; j < BN / 32; ++j) {
            int r = wn + j * 16 + fr;
            int off = r * 32 + (kc ^ ((r >> 1) & 3)) * 8;
            bfh[j] = *(const bf16x8*)&BsH[off];
            bfl[j] = *(const bf16x8*)&BsL[off];
        }
#pragma unroll
        for (int i = 0; i < 4; ++i)
#pragma unroll
            for (int j = 0; j < BN / 32; ++j) {
                acc[i][j] = __builtin_amdgcn_mfma_f32_16x16x32_bf16(afh[i], bfh[j], acc[i][j], 0, 0, 0);
                acc[i][j] = __builtin_amdgcn_mfma_f32_16x16x32_bf16(afl[i], bfh[j], acc[i][j], 0, 0, 0);
                acc[i][j] = __builtin_amdgcn_mfma_f32_16x16x32_bf16(afh[i], bfl[j], acc[i][j], 0, 0, 0);
            }
    }

    // epilogue: C/D layout col=lane&15, row=(lane>>4)*4+reg  [m89/m91]
    const int row0 = m0 + wm + (lane >> 4) * 4;
    const int colb = n0 + wn + fr;
#pragma unroll
    for (int i = 0; i < 4; ++i)
#pragma unroll
        for (int j = 0; j < BN / 32; ++j) {
            int col = colb + j * 16;
            if (col < Nstore) {
#pragma unroll
                for (int t = 0; t < 4; ++t)
                    C[(size_t)(row0 + i * 16 + t) * ldc + col] = acc[i][j][t];
            }
        }
}

// ---------------------------------------------------------------------------
// split-K=2 partial reduce
// ---------------------------------------------------------------------------
__global__ __launch_bounds__(256) void reduce2_kernel(const float* __restrict__ p,
                                                      float* __restrict__ out, int n) {
    int i4 = (blockIdx.x * 256 + threadIdx.x) * 4;
    float4 a = *(const float4*)&p[i4];
    float4 b = *(const float4*)&p[(size_t)n + i4];
    *(float4*)&out[i4] = make_float4(a.x + b.x, a.y + b.y, a.z + b.z, a.w + b.w);
}

// ---------------------------------------------------------------------------
// depthwise causal conv (k=4) + SiLU -> xh; first 64 blocks also do dt/a_bar.
// ---------------------------------------------------------------------------
__global__ __launch_bounds__(256) void conv_silu_kernel(const float* __restrict__ zx,
                                                        const float* __restrict__ conv_w,
                                                        const float* __restrict__ conv_b,
                                                        const float* __restrict__ dt_bias,
                                                        const float* __restrict__ A_log,
                                                        float* __restrict__ xh,
                                                        float* __restrict__ abar) {
    int idx = blockIdx.x * 256 + threadIdx.x;
    int c = idx & (D_INNER - 1);
    int m = idx >> 11;
    int l = m & (SEQ - 1);
    float acc = conv_b[c];
#pragma unroll
    for (int k = 0; k < D_CONV; ++k) {
        int lj = l + k - (D_CONV - 1);
        if (lj >= 0)
            acc = fmaf(zx[(size_t)(m + k - (D_CONV - 1)) * NPROJ + OFF_XC + c],
                       conv_w[c * D_CONV + k], acc);
    }
    xh[idx] = acc / (1.f + expf(-acc));

    if (blockIdx.x < (M_ROWS * N_HEADS) / 256) {
        int di = blockIdx.x * 256 + threadIdx.x;
        int h = di & (N_HEADS - 1);
        int dm = di >> 3;
        float v = zx[(size_t)dm * NPROJ + OFF_DT + h] + dt_bias[h];
        abar[di] = expf(softplus_f(v) * -expf(A_log[h]));
    }
}

// ---------------------------------------------------------------------------
// PASS 1: local scan within a 64-step chunk (zero initial state).
// yscan gets y_local + D*x folded in.
// ---------------------------------------------------------------------------
#define SCHUNK 32
__global__ __launch_bounds__(256) void scan_local_kernel(const float* __restrict__ zx,
                                                         const float* __restrict__ xh,
                                                         const float* __restrict__ abar,
                                                         const float* __restrict__ Dp,
                                                         float* __restrict__ yscan,
                                                         float* __restrict__ Sloc) {
    const int blk = blockIdx.x;          // 0..1023
    const int dq = blk & 3;
    const int c  = (blk >> 2) & (N_CHUNK - 1);
    const int bh = blk >> 6;
    const int hh = bh & (N_HEADS - 1);
    const int b  = bh >> 3;
    const int t  = threadIdx.x;
    const int d_local = t >> 2;
    const int g = t & 3;

    __shared__ float aS[SCHUNK];
    __shared__ float bS[SCHUNK][D_STATE];
    __shared__ float cS[SCHUNK][D_STATE];
    __shared__ float xS[SCHUNK][64];

    float hst[16];
#pragma unroll
    for (int i = 0; i < 16; ++i) hst[i] = 0.f;

    const int m0base = b * SEQ + c * CHUNK;
    const int xcol = hh * HEAD_DIM + dq * 64;
    const float Dh = Dp[hh];

    for (int st = 0; st < CHUNK / SCHUNK; ++st) {
        const int m0 = m0base + st * SCHUNK;
        __syncthreads();
#pragma unroll
        for (int i = 0; i < 8; ++i) {
            int idx = t + i * 256;
            int r = idx >> 6, n = idx & 63;
            size_t rowz = (size_t)(m0 + r) * NPROJ;
            bS[r][n] = zx[rowz + OFF_B + n];
            cS[r][n] = zx[rowz + OFF_C + n];
            xS[r][n] = xh[(size_t)(m0 + r) * D_INNER + xcol + n];
        }
        if (t < SCHUNK) aS[t] = abar[(m0 + t) * N_HEADS + hh];
        __syncthreads();

        for (int r = 0; r < SCHUNK; ++r) {
            float a = aS[r];
            float xd = xS[r][d_local];
            const float* bp = &bS[r][g * 16];
            const float* cp = &cS[r][g * 16];
            float acc0 = 0.f, acc1 = 0.f;
#pragma unroll
            for (int i = 0; i < 16; i += 2) {
                hst[i]     = fmaf(a, hst[i],     bp[i]     * xd);
                acc0       = fmaf(hst[i],     cp[i],     acc0);
                hst[i + 1] = fmaf(a, hst[i + 1], bp[i + 1] * xd);
                acc1       = fmaf(hst[i + 1], cp[i + 1], acc1);
            }
            float acc = acc0 + acc1;
            acc += __shfl_xor(acc, 1);
            acc += __shfl_xor(acc, 2);
            if (g == 0)
                yscan[(size_t)(m0 + r) * D_INNER + xcol + d_local] = fmaf(Dh, xd, acc);
        }
    }

    size_t sbase = ((size_t)(bh * N_CHUNK + c) * HEAD_DIM + dq * 64 + d_local) * D_STATE + g * 16;
#pragma unroll
    for (int i = 0; i < 16; i += 4)
        *(float4*)&Sloc[sbase + i] = make_float4(hst[i], hst[i+1], hst[i+2], hst[i+3]);
}

// ---------------------------------------------------------------------------
// PASS 2: inter-chunk recurrence in place on Sloc -> H_init(c).
// ---------------------------------------------------------------------------
__global__ __launch_bounds__(256) void scan_combine_kernel(const float* __restrict__ abar,
                                                           float* __restrict__ Sloc) {
    const int blk = blockIdx.x;
    const int ds = blk & 15;
    const int bh = blk >> 4;
    const int hh = bh & (N_HEADS - 1);
    const int b  = bh >> 3;
    const int t  = threadIdx.x;

    __shared__ float PS[N_CHUNK];
    if (t < N_CHUNK) {
        float p = 1.f;
        int mbase = b * SEQ + t * CHUNK;
        for (int j = 0; j < CHUNK; ++j)
            p *= abar[(mbase + j) * N_HEADS + hh];
        PS[t] = p;
    }
    __syncthreads();

    float H[4] = {0.f, 0.f, 0.f, 0.f};
    for (int c = 0; c < N_CHUNK; ++c) {
        size_t base = (size_t)(bh * N_CHUNK + c) * STATE_PER_BH + ds * 1024 + t;
        float Sv[4];
#pragma unroll
        for (int i = 0; i < 4; ++i) Sv[i] = Sloc[base + i * 256];
#pragma unroll
        for (int i = 0; i < 4; ++i) Sloc[base + i * 256] = H[i];
        float P = PS[c];
#pragma unroll
        for (int i = 0; i < 4; ++i) H[i] = fmaf(P, H[i], Sv[i]);
    }
}

// ---------------------------------------------------------------------------
// PASS 3: y_t += cumA(t) * (C_t . H_init(chunk)).
// ---------------------------------------------------------------------------
__global__ __launch_bounds__(256) void scan_correct_kernel(const float* __restrict__ zx,
                                                           const float* __restrict__ abar,
                                                           const float* __restrict__ Hini,
                                                           float* __restrict__ yscan) {
    const int blk = blockIdx.x;
    const int dq = blk & 3;
    const int c  = (blk >> 2) & (N_CHUNK - 1);
    const int bh = blk >> 6;
    const int hh = bh & (N_HEADS - 1);
    const int b  = bh >> 3;
    const int t  = threadIdx.x;
    const int d_local = t >> 2;
    const int g = t & 3;

    __shared__ float cS[CHUNK][D_STATE];
    __shared__ float aS[CHUNK];

    const int m0 = b * SEQ + c * CHUNK;
#pragma unroll
    for (int i = 0; i < 16; ++i) {
        int idx = t + i * 256;
        int r = idx >> 6, n = idx & 63;
        cS[r][n] = zx[(size_t)(m0 + r) * NPROJ + OFF_C + n];
    }
    if (t < CHUNK) aS[t] = abar[(m0 + t) * N_HEADS + hh];

    float H[16];
    size_t hbase = ((size_t)(bh * N_CHUNK + c) * HEAD_DIM + dq * 64 + d_local) * D_STATE + g * 16;
#pragma unroll
    for (int i = 0; i < 16; i += 4) {
        float4 v = *(const float4*)&Hini[hbase + i];
        H[i] = v.x; H[i+1] = v.y; H[i+2] = v.z; H[i+3] = v.w;
    }
    __syncthreads();

    const int xcol = hh * HEAD_DIM + dq * 64;
    float cum = 1.f;
    for (int r = 0; r < CHUNK; ++r) {
        cum *= aS[r];
        const float* cp = &cS[r][g * 16];
        float acc0 = 0.f, acc1 = 0.f;
#pragma unroll
        for (int i = 0; i < 16; i += 2) {
            acc0 = fmaf(H[i],     cp[i],     acc0);
            acc1 = fmaf(H[i + 1], cp[i + 1], acc1);
        }
        float acc = acc0 + acc1;
        acc += __shfl_xor(acc, 1);
        acc += __shfl_xor(acc, 2);
        if (g == 0)
            yscan[(size_t)(m0 + r) * D_INNER + xcol + d_local] += cum * acc;
    }
}

// ---------------------------------------------------------------------------
// y = yscan * silu(z); RMSNorm over D_INNER; emits bf16 hi/lo split.
// (D*x folded into yscan by scan pass 1)
// ---------------------------------------------------------------------------
__global__ __launch_bounds__(256) void gate_norm_kernel(const float* __restrict__ zx,
                                                        const float* __restrict__ nw,
                                                        const float* __restrict__ y,
                                                        u16* __restrict__ ybf_h,
                                                        u16* __restrict__ ybf_l) {
    const int m = blockIdx.x;
    const int t = threadIdx.x;
    const size_t rowz = (size_t)m * NPROJ;
    const size_t rowy = (size_t)m * D_INNER;

    float v[8];
    float ss = 0.f;
#pragma unroll
    for (int i = 0; i < 8; ++i) {
        int c = t + i * 256;
        float ys = y[rowy + c];
        float z  = zx[rowz + OFF_Z + c];
        float gated = ys * (z / (1.f + expf(-z)));
        v[i] = gated;
        ss += gated * gated;
    }
#pragma unroll
    for (int off = 1; off < 64; off <<= 1) ss += __shfl_xor(ss, off);

    __shared__ float red[4];
    if ((t & 63) == 0) red[t >> 6] = ss;
    __syncthreads();
    float tot = red[0] + red[1] + red[2] + red[3];
    float scale = 1.f / sqrtf(tot / (float)D_INNER + 1e-6f);

#pragma unroll
    for (int i = 0; i < 8; ++i) {
        int c = t + i * 256;
        float o = v[i] * scale * nw[c];
        u16 h = f2bf(o);
        ybf_h[rowy + c] = h;
        ybf_l[rowy + c] = f2bf(o - bf2f(h));
    }
}

// ---------------------------------------------------------------------------
extern "C" void kernel_launch(void* const* d_in, const int* in_sizes, int n_in,
                              void* d_out, int out_size, void* d_ws, size_t ws_size,
                              hipStream_t stream) {
    const float* x         = (const float*)d_in[0];
    const float* in_proj_w = (const float*)d_in[1];
    const float* conv_w    = (const float*)d_in[2];
    const float* conv_b    = (const float*)d_in[3];
    const float* A_log     = (const float*)d_in[4];
    const float* D_param   = (const float*)d_in[5];
    const float* dt_bias   = (const float*)d_in[6];
    const float* norm_w    = (const float*)d_in[7];
    const float* out_proj_w= (const float*)d_in[8];
    float* out = (float*)d_out;

    float* ws   = (float*)d_ws;
    float* zx   = ws;                                   // M_ROWS * NPROJ fp32   (34.7 MB)
    float* xh   = zx  + (size_t)M_ROWS * NPROJ;         // M_ROWS * D_INNER fp32 (16.8 MB)
    float* ysc  = xh  + (size_t)M_ROWS * D_INNER;       // M_ROWS * D_INNER fp32 (16.8 MB)
    float* ab   = ysc + (size_t)M_ROWS * D_INNER;       // M_ROWS * N_HEADS fp32
    float* Sloc = ab  + (size_t)M_ROWS * N_HEADS;       // 4.19M fp32 (16.8 MB)

    // bf16 hi/lo overlays on regions DEAD at time of use (launch order below):
    u16* xbf_h  = (u16*)ysc;                            // ysc dead until scan pass1
    u16* xbf_l  = xbf_h + (size_t)M_ROWS * DIM;
    u16* wibf_h = (u16*)xh;                             // xh dead until conv
    u16* wibf_l = (u16*)Sloc;                           // Sloc dead until scan pass1
    u16* ybf_h  = (u16*)Sloc;                           // Sloc dead after scan pass3
    u16* ybf_l  = ybf_h + (size_t)M_ROWS * D_INNER;
    u16* wobf_h = (u16*)xh;                             // xh dead after scan pass1
    u16* wobf_l = wobf_h + (size_t)DIM * D_INNER;
    float* pbuf = zx;                                   // zx dead after gate_norm (16.8 <= 34.7 MB)

    // merged split casts for GEMM1 (x + padded in_proj_w)
    {
        int n0 = M_ROWS * DIM;                          // 2.10M
        int n1t = NPROJ_PAD * DIM;                      // 4.46M
        cast_split2_kernel<<<(n0 + n1t) / 1024, 256, 0, stream>>>(
            x, xbf_h, xbf_l, n0,
            in_proj_w, wibf_h, wibf_l, NPROJ * DIM, n1t);
    }

    // 1) zxBCdt = x @ in_proj_w^T  (2048 x 4232, K=1024), split bf16 MFMA
    gemm_mfma3<128><<<dim3(NPROJ_PAD / 128, M_ROWS / 128, 1), 256, 0, stream>>>(
        xbf_h, xbf_l, wibf_h, wibf_l, zx, DIM, NPROJ, NPROJ, 0);

    // 2) conv + silu -> xh (+ fused dt/a_bar -> ab)
    conv_silu_kernel<<<(M_ROWS * D_INNER) / 256, 256, 0, stream>>>(
        zx, conv_w, conv_b, dt_bias, A_log, xh, ab);

    // 3) chunk-parallel scan (D*x folded into pass 1)
    scan_local_kernel<<<BATCH * N_HEADS * N_CHUNK * 4, 256, 0, stream>>>(
        zx, xh, ab, D_param, ysc, Sloc);
    scan_combine_kernel<<<BATCH * N_HEADS * 16, 256, 0, stream>>>(ab, Sloc);
    scan_correct_kernel<<<BATCH * N_HEADS * N_CHUNK * 4, 256, 0, stream>>>(
        zx, ab, Sloc, ysc);

    // 4) gate + rmsnorm, emits split-bf16 y
    gate_norm_kernel<<<M_ROWS, 256, 0, stream>>>(zx, norm_w, ysc, ybf_h, ybf_l);

    // 5) split cast for GEMM2 weights
    cast_split_kernel<<<(DIM * D_INNER) / 1024, 256, 0, stream>>>(
        out_proj_w, wobf_h, wobf_l, DIM * D_INNER);

    // 6) out = y @ out_proj_w^T  (2048 x 1024, K=2048), BN=64, split-K=2 -> pbuf
    gemm_mfma3<64><<<dim3(DIM / 64, M_ROWS / 128, 2), 256, 0, stream>>>(
        ybf_h, ybf_l, wobf_h, wobf_l, pbuf, D_INNER, DIM, DIM,
        (size_t)M_ROWS * DIM);

    // 7) reduce partials -> out
    reduce2_kernel<<<(M_ROWS * DIM) / 1024, 256, 0, stream>>>(pbuf, out, M_ROWS * DIM);
}

// Round 8
// 276.919 us; speedup vs baseline: 1.2213x; 1.1125x over previous
//
#include <hip/hip_runtime.h>
#include <hip/hip_bf16.h>
#include <math.h>

#define DIM      1024
#define D_STATE  64
#define D_CONV   4
#define N_HEADS  8
#define D_INNER  2048
#define HEAD_DIM 256
#define NPROJ    4232      // 2048 + 2048 + 8 + 64 + 64
#define BATCH    2
#define SEQ      1024
#define M_ROWS   (BATCH * SEQ)   // 2048
#define OFF_Z    0
#define OFF_XC   2048
#define OFF_DT   4096
#define OFF_B    4104
#define OFF_C    4168

#define CHUNK    64
#define N_CHUNK  (SEQ / CHUNK)    // 16
#define STATE_PER_BH (HEAD_DIM * D_STATE)   // 16384 floats

#define NPROJ_PAD 4352            // 34 * 128 (GEMM1 grid only; B rows guarded)
#define PADT 72                   // padded u16 row pitch for 64-wide LDS tiles

typedef unsigned short u16;
typedef __bf16 bf16x8 __attribute__((ext_vector_type(8)));
typedef float  f32x4  __attribute__((ext_vector_type(4)));

__device__ __forceinline__ u16 f2bf(float f) {
    unsigned int u = __float_as_uint(f);
    unsigned int r = (u + 0x7FFFu + ((u >> 16) & 1u)) >> 16;   // RNE
    return (u16)r;
}
__device__ __forceinline__ float bf2f(u16 h) {
    return __uint_as_float(((unsigned int)h) << 16);
}

__device__ __forceinline__ void load_lds16(const void* g, void* l) {
    __builtin_amdgcn_global_load_lds((const __attribute__((address_space(1))) unsigned int*)g,
                                     (__attribute__((address_space(3))) unsigned int*)l,
                                     16, 0, 0);
}

__device__ __forceinline__ float softplus_f(float v) {
    return (v > 20.f) ? v : log1pf(expf(v));
}

// ---------------------------------------------------------------------------
// merged split-cast for two segments (x and in_proj_w), no padding.
// ---------------------------------------------------------------------------
__global__ __launch_bounds__(256) void cast_split2_kernel(
        const float* __restrict__ s0, u16* __restrict__ h0, u16* __restrict__ l0, int n0,
        const float* __restrict__ s1, u16* __restrict__ h1, u16* __restrict__ l1, int n1) {
    int i4 = (blockIdx.x * 256 + threadIdx.x) * 4;
    const float* src; u16 *hi, *lo;
    if (i4 < n0) {
        src = s0; hi = h0; lo = l0;
    } else {
        i4 -= n0;
        if (i4 >= n1) return;
        src = s1; hi = h1; lo = l1;
    }
    float4 v = *(const float4*)&src[i4];
    ushort4 h, l;
    h.x = f2bf(v.x); h.y = f2bf(v.y); h.z = f2bf(v.z); h.w = f2bf(v.w);
    l.x = f2bf(v.x - bf2f(h.x));
    l.y = f2bf(v.y - bf2f(h.y));
    l.z = f2bf(v.z - bf2f(h.z));
    l.w = f2bf(v.w - bf2f(h.w));
    *(ushort4*)&hi[i4] = h;
    *(ushort4*)&lo[i4] = l;
}

__global__ __launch_bounds__(256) void cast_split_kernel(const float* __restrict__ src,
                                                         u16* __restrict__ hi,
                                                         u16* __restrict__ lo, int n) {
    int i4 = (blockIdx.x * 256 + threadIdx.x) * 4;
    if (i4 >= n) return;
    float4 v = *(const float4*)&src[i4];
    ushort4 h, l;
    h.x = f2bf(v.x); h.y = f2bf(v.y); h.z = f2bf(v.z); h.w = f2bf(v.w);
    l.x = f2bf(v.x - bf2f(h.x));
    l.y = f2bf(v.y - bf2f(h.y));
    l.z = f2bf(v.z - bf2f(h.z));
    l.w = f2bf(v.w - bf2f(h.w));
    *(ushort4*)&hi[i4] = h;
    *(ushort4*)&lo[i4] = l;
}

// ---------------------------------------------------------------------------
// split-bf16 MFMA GEMM: C = A @ B^T, A ~ Ah+Al, B ~ Bh+Bl, fp32 accum.
// acc += Ah*Bh + Al*Bh + Ah*Bl.  BM=128 x BN tile, BK=32, 256 thr (2x2 waves).
// B rows guarded by NrowsB (no padded allocation needed); stores by Nstore.
// Optional split-K via gridDim.z; slice z writes C + z*zstride.
// ---------------------------------------------------------------------------
template<int BN>
__global__ __launch_bounds__(256) void gemm_mfma3(const u16* __restrict__ Ah,
                                                  const u16* __restrict__ Al,
                                                  const u16* __restrict__ Bh,
                                                  const u16* __restrict__ Bl,
                                                  float* __restrict__ C,
                                                  int K, int ldc, int Nstore,
                                                  int NrowsB, size_t zstride) {
    __shared__ u16 AsH[128 * 32];
    __shared__ u16 AsL[128 * 32];
    __shared__ u16 BsH[BN * 32];
    __shared__ u16 BsL[BN * 32];

    const int tid  = threadIdx.x;
    const int wave = tid >> 6;
    const int lane = tid & 63;
    const int fr   = lane & 15;
    const int kc   = lane >> 4;
    const int m0   = blockIdx.y * 128;
    const int n0   = blockIdx.x * BN;
    const int wm   = (wave & 1) * 64;
    const int wn   = (wave >> 1) * (BN / 2);

    const int kPer = K / gridDim.z;
    const int kBeg = blockIdx.z * kPer;
    C += (size_t)blockIdx.z * zstride;

    f32x4 acc[4][BN / 32];
#pragma unroll
    for (int i = 0; i < 4; ++i)
#pragma unroll
        for (int j = 0; j < BN / 32; ++j) acc[i][j] = (f32x4)0.f;

    for (int k0 = kBeg; k0 < kBeg + kPer; k0 += 32) {
        __syncthreads();
#pragma unroll
        for (int q = 0; q < 2; ++q) {
            int s = wave * 128 + q * 64 + lane;
            int r = s >> 2, pc = s & 3;
            int gc = pc ^ ((r >> 1) & 3);
            size_t goff = (size_t)(m0 + r) * K + k0 + gc * 8;
            load_lds16(Ah + goff, &AsH[(wave * 128 + q * 64) * 8]);
            load_lds16(Al + goff, &AsL[(wave * 128 + q * 64) * 8]);
        }
#pragma unroll
        for (int q = 0; q < BN / 64; ++q) {
            int s = wave * BN + q * 64 + lane;
            int r = s >> 2, pc = s & 3;
            int gc = pc ^ ((r >> 1) & 3);
            if (n0 + r < NrowsB) {   // OOB rows: stale LDS, results never stored
                size_t goff = (size_t)(n0 + r) * K + k0 + gc * 8;
                load_lds16(Bh + goff, &BsH[(wave * BN + q * 64) * 8]);
                load_lds16(Bl + goff, &BsL[(wave * BN + q * 64) * 8]);
            }
        }
        __syncthreads();

        bf16x8 afh[4], afl[4];
#pragma unroll
        for (int i = 0; i < 4; ++i) {
            int r = wm + i * 16 + fr;
            int off = r * 32 + (kc ^ ((r >> 1) & 3)) * 8;
            afh[i] = *(const bf16x8*)&AsH[off];
            afl[i] = *(const bf16x8*)&AsL[off];
        }
        bf16x8 bfh[BN / 32], bfl[BN / 32];
#pragma unroll
        for (int j = 0; j < BN / 32; ++j) {
            int r = wn + j * 16 + fr;
            int off = r * 32 + (kc ^ ((r >> 1) & 3)) * 8;
            bfh[j] = *(const bf16x8*)&BsH[off];
            bfl[j] = *(const bf16x8*)&BsL[off];
        }
#pragma unroll
        for (int i = 0; i < 4; ++i)
#pragma unroll
            for (int j = 0; j < BN / 32; ++j) {
                acc[i][j] = __builtin_amdgcn_mfma_f32_16x16x32_bf16(afh[i], bfh[j], acc[i][j], 0, 0, 0);
                acc[i][j] = __builtin_amdgcn_mfma_f32_16x16x32_bf16(afl[i], bfh[j], acc[i][j], 0, 0, 0);
                acc[i][j] = __builtin_amdgcn_mfma_f32_16x16x32_bf16(afh[i], bfl[j], acc[i][j], 0, 0, 0);
            }
    }

    // epilogue: C/D layout col=lane&15, row=(lane>>4)*4+reg  [m89/m91]
    const int row0 = m0 + wm + (lane >> 4) * 4;
    const int colb = n0 + wn + fr;
#pragma unroll
    for (int i = 0; i < 4; ++i)
#pragma unroll
        for (int j = 0; j < BN / 32; ++j) {
            int col = colb + j * 16;
            if (col < Nstore) {
#pragma unroll
                for (int t = 0; t < 4; ++t)
                    C[(size_t)(row0 + i * 16 + t) * ldc + col] = acc[i][j][t];
            }
        }
}

// ---------------------------------------------------------------------------
// split-K=2 partial reduce
// ---------------------------------------------------------------------------
__global__ __launch_bounds__(256) void reduce2_kernel(const float* __restrict__ p,
                                                      float* __restrict__ out, int n) {
    int i4 = (blockIdx.x * 256 + threadIdx.x) * 4;
    float4 a = *(const float4*)&p[i4];
    float4 b = *(const float4*)&p[(size_t)n + i4];
    *(float4*)&out[i4] = make_float4(a.x + b.x, a.y + b.y, a.z + b.z, a.w + b.w);
}

// ---------------------------------------------------------------------------
// depthwise causal conv (k=4) + SiLU -> xh (bf16); first 64 blocks: dt/a_bar.
// ---------------------------------------------------------------------------
__global__ __launch_bounds__(256) void conv_silu_kernel(const float* __restrict__ zx,
                                                        const float* __restrict__ conv_w,
                                                        const float* __restrict__ conv_b,
                                                        const float* __restrict__ dt_bias,
                                                        const float* __restrict__ A_log,
                                                        u16* __restrict__ xh,
                                                        float* __restrict__ abar) {
    int idx = blockIdx.x * 256 + threadIdx.x;
    int c = idx & (D_INNER - 1);
    int m = idx >> 11;
    int l = m & (SEQ - 1);
    float acc = conv_b[c];
#pragma unroll
    for (int k = 0; k < D_CONV; ++k) {
        int lj = l + k - (D_CONV - 1);
        if (lj >= 0)
            acc = fmaf(zx[(size_t)(m + k - (D_CONV - 1)) * NPROJ + OFF_XC + c],
                       conv_w[c * D_CONV + k], acc);
    }
    xh[idx] = f2bf(acc / (1.f + expf(-acc)));

    if (blockIdx.x < (M_ROWS * N_HEADS) / 256) {
        int di = blockIdx.x * 256 + threadIdx.x;
        int h = di & (N_HEADS - 1);
        int dm = di >> 3;
        float v = zx[(size_t)dm * NPROJ + OFF_DT + h] + dt_bias[h];
        abar[di] = expf(softplus_f(v) * -expf(A_log[h]));
    }
}

// ---------------------------------------------------------------------------
// PASS 1 (SSD/MFMA): per (b,h,chunk,dq-64-slice):
//   G = C@B^T; P[t][s] = exp(A(SD[t]-SD[s]))*G (s<=t);
//   Y_local = P@X; S_c = (w2*B)^T @ X.
// All matmuls via 16x16x32 bf16 MFMA. X read as bf16 from xh.
// ---------------------------------------------------------------------------
__global__ __launch_bounds__(256) void scan_local_mfma(const float* __restrict__ zx,
                                                       const u16* __restrict__ xh,
                                                       const float* __restrict__ dt_bias,
                                                       const float* __restrict__ A_log,
                                                       float* __restrict__ yscan,
                                                       float* __restrict__ Sloc) {
    const int blk = blockIdx.x;                 // 0..1023
    const int dq = blk & 3;
    const int c  = (blk >> 2) & (N_CHUNK - 1);
    const int bh = blk >> 6;
    const int hh = bh & (N_HEADS - 1);
    const int b  = bh >> 3;
    const int t    = threadIdx.x;
    const int wave = t >> 6;
    const int lane = t & 63;
    const int fr   = lane & 15;
    const int quad = lane >> 4;

    __shared__ float SDs[64];
    __shared__ u16 Ct [64 * PADT];
    __shared__ u16 Bt [64 * PADT];
    __shared__ u16 BwT[64 * PADT];
    __shared__ u16 Ps [64 * PADT];
    __shared__ u16 XsT[64 * PADT];              // [d][t] for this 64-d slice

    const int m0   = b * SEQ + c * CHUNK;
    const int xcol = hh * HEAD_DIM + dq * 64;
    const float Ahd = -expf(A_log[hh]);
    const float dtb = dt_bias[hh];

    // dt inclusive prefix sum (wave 0)
    if (t < 64) {
        float d = softplus_f(zx[(size_t)(m0 + t) * NPROJ + OFF_DT + hh] + dtb);
#pragma unroll
        for (int off = 1; off < 64; off <<= 1) {
            float o = __shfl_up(d, off);
            if (lane >= off) d += o;
        }
        SDs[t] = d;
    }
    __syncthreads();
    const float SD63 = SDs[63];

    // stage B, C, Bw^T, X^T tiles (fp32->bf16 / bf16 passthrough)
#pragma unroll
    for (int i = 0; i < 16; ++i) {
        int idx = t + i * 256;
        int r = idx >> 6, n = idx & 63;
        size_t rowz = (size_t)(m0 + r) * NPROJ;
        float bv = zx[rowz + OFF_B + n];
        float cv = zx[rowz + OFF_C + n];
        Bt[r * PADT + n] = f2bf(bv);
        Ct[r * PADT + n] = f2bf(cv);
        float w2 = expf(Ahd * (SD63 - SDs[r]));
        BwT[n * PADT + r] = f2bf(bv * w2);
        // X^T: d = n index here reused
        XsT[n * PADT + r] = xh[(size_t)(m0 + r) * D_INNER + xcol + n];
    }
    __syncthreads();

    const int tm0 = wave * 16;

    // G = C@B^T  (this wave's 16 t-rows x 64 s)
    f32x4 g[4];
#pragma unroll
    for (int j = 0; j < 4; ++j) g[j] = (f32x4)0.f;
#pragma unroll
    for (int kk = 0; kk < 2; ++kk) {
        bf16x8 af = *(const bf16x8*)&Ct[(tm0 + fr) * PADT + kk * 32 + quad * 8];
#pragma unroll
        for (int j = 0; j < 4; ++j) {
            bf16x8 bf = *(const bf16x8*)&Bt[(j * 16 + fr) * PADT + kk * 32 + quad * 8];
            g[j] = __builtin_amdgcn_mfma_f32_16x16x32_bf16(af, bf, g[j], 0, 0, 0);
        }
    }
    // mask + decay -> Ps (same-wave rows only; no barrier needed)
    {
        int trow = tm0 + quad * 4;
#pragma unroll
        for (int j = 0; j < 4; ++j) {
#pragma unroll
            for (int reg = 0; reg < 4; ++reg) {
                int tt = trow + reg, ss = j * 16 + fr;
                float val = 0.f;
                if (ss <= tt) val = expf(Ahd * (SDs[tt] - SDs[ss])) * g[j][reg];
                Ps[tt * PADT + ss] = f2bf(val);
            }
        }
    }

    // Y_local = P @ X   (a = Ps rows[t], b = XsT rows[d])
    f32x4 ya[4];
#pragma unroll
    for (int j = 0; j < 4; ++j) ya[j] = (f32x4)0.f;
#pragma unroll
    for (int kk = 0; kk < 2; ++kk) {
        bf16x8 af = *(const bf16x8*)&Ps[(tm0 + fr) * PADT + kk * 32 + quad * 8];
#pragma unroll
        for (int j = 0; j < 4; ++j) {
            bf16x8 bf = *(const bf16x8*)&XsT[(j * 16 + fr) * PADT + kk * 32 + quad * 8];
            ya[j] = __builtin_amdgcn_mfma_f32_16x16x32_bf16(af, bf, ya[j], 0, 0, 0);
        }
    }
#pragma unroll
    for (int j = 0; j < 4; ++j)
#pragma unroll
        for (int reg = 0; reg < 4; ++reg) {
            int tt = tm0 + quad * 4 + reg;
            int dd = j * 16 + fr;
            yscan[(size_t)(m0 + tt) * D_INNER + xcol + dd] = ya[j][reg];
        }

    // S_c = Bw^T @ X  (a = BwT rows[n], b = XsT rows[d]) -> Sloc[n][d]
    f32x4 sa[4];
#pragma unroll
    for (int j = 0; j < 4; ++j) sa[j] = (f32x4)0.f;
#pragma unroll
    for (int kk = 0; kk < 2; ++kk) {
        bf16x8 af = *(const bf16x8*)&BwT[(tm0 + fr) * PADT + kk * 32 + quad * 8];
#pragma unroll
        for (int j = 0; j < 4; ++j) {
            bf16x8 bf = *(const bf16x8*)&XsT[(j * 16 + fr) * PADT + kk * 32 + quad * 8];
            sa[j] = __builtin_amdgcn_mfma_f32_16x16x32_bf16(af, bf, sa[j], 0, 0, 0);
        }
    }
    size_t sbase = (size_t)(bh * N_CHUNK + c) * STATE_PER_BH;
#pragma unroll
    for (int j = 0; j < 4; ++j)
#pragma unroll
        for (int reg = 0; reg < 4; ++reg) {
            int nn = tm0 + quad * 4 + reg;
            int dd = j * 16 + fr;
            Sloc[sbase + (size_t)nn * HEAD_DIM + dq * 64 + dd] = sa[j][reg];
        }
}

// ---------------------------------------------------------------------------
// PASS 2: inter-chunk recurrence in place on Sloc -> H_init(c). (layout-flat)
// ---------------------------------------------------------------------------
__global__ __launch_bounds__(256) void scan_combine_kernel(const float* __restrict__ abar,
                                                           float* __restrict__ Sloc) {
    const int blk = blockIdx.x;
    const int ds = blk & 15;
    const int bh = blk >> 4;
    const int hh = bh & (N_HEADS - 1);
    const int b  = bh >> 3;
    const int t  = threadIdx.x;

    __shared__ float PS[N_CHUNK];
    if (t < N_CHUNK) {
        float p = 1.f;
        int mbase = b * SEQ + t * CHUNK;
        for (int j = 0; j < CHUNK; ++j)
            p *= abar[(mbase + j) * N_HEADS + hh];
        PS[t] = p;
    }
    __syncthreads();

    float H[4] = {0.f, 0.f, 0.f, 0.f};
    for (int c = 0; c < N_CHUNK; ++c) {
        size_t base = (size_t)(bh * N_CHUNK + c) * STATE_PER_BH + ds * 1024 + t;
        float Sv[4];
#pragma unroll
        for (int i = 0; i < 4; ++i) Sv[i] = Sloc[base + i * 256];
#pragma unroll
        for (int i = 0; i < 4; ++i) Sloc[base + i * 256] = H[i];
        float P = PS[c];
#pragma unroll
        for (int i = 0; i < 4; ++i) H[i] = fmaf(P, H[i], Sv[i]);
    }
}

// ---------------------------------------------------------------------------
// PASS 3 (MFMA): Y[t][d] += cum[t] * (C @ H)  with H from Sloc[n][d].
// ---------------------------------------------------------------------------
__global__ __launch_bounds__(256) void scan_corr_mfma(const float* __restrict__ zx,
                                                      const float* __restrict__ dt_bias,
                                                      const float* __restrict__ A_log,
                                                      const float* __restrict__ Hini,
                                                      float* __restrict__ yscan) {
    const int blk = blockIdx.x;
    const int dq = blk & 3;
    const int c  = (blk >> 2) & (N_CHUNK - 1);
    const int bh = blk >> 6;
    const int hh = bh & (N_HEADS - 1);
    const int b  = bh >> 3;
    const int t    = threadIdx.x;
    const int wave = t >> 6;
    const int lane = t & 63;
    const int fr   = lane & 15;
    const int quad = lane >> 4;

    __shared__ float SDs[64];
    __shared__ u16 Ct [64 * PADT];
    __shared__ u16 Hdn[64 * PADT];              // [d][n] bf16

    const int m0   = b * SEQ + c * CHUNK;
    const int xcol = hh * HEAD_DIM + dq * 64;
    const float Ahd = -expf(A_log[hh]);
    const float dtb = dt_bias[hh];

    if (t < 64) {
        float d = softplus_f(zx[(size_t)(m0 + t) * NPROJ + OFF_DT + hh] + dtb);
#pragma unroll
        for (int off = 1; off < 64; off <<= 1) {
            float o = __shfl_up(d, off);
            if (lane >= off) d += o;
        }
        SDs[t] = d;
    }

    size_t hbase = (size_t)(bh * N_CHUNK + c) * STATE_PER_BH;
#pragma unroll
    for (int i = 0; i < 16; ++i) {
        int idx = t + i * 256;
        int r = idx >> 6, n = idx & 63;       // r: row index (t or n), n: col
        Ct[r * PADT + n] = f2bf(zx[(size_t)(m0 + r) * NPROJ + OFF_C + n]);
        // H: read [n=r][d=n-col] coalesced, store transposed [d][n]
        Hdn[n * PADT + r] = f2bf(Hini[hbase + (size_t)r * HEAD_DIM + dq * 64 + n]);
    }
    __syncthreads();

    const int tm0 = wave * 16;
    f32x4 ya[4];
#pragma unroll
    for (int j = 0; j < 4; ++j) ya[j] = (f32x4)0.f;
#pragma unroll
    for (int kk = 0; kk < 2; ++kk) {
        bf16x8 af = *(const bf16x8*)&Ct[(tm0 + fr) * PADT + kk * 32 + quad * 8];
#pragma unroll
        for (int j = 0; j < 4; ++j) {
            bf16x8 bf = *(const bf16x8*)&Hdn[(j * 16 + fr) * PADT + kk * 32 + quad * 8];
            ya[j] = __builtin_amdgcn_mfma_f32_16x16x32_bf16(af, bf, ya[j], 0, 0, 0);
        }
    }
#pragma unroll
    for (int reg = 0; reg < 4; ++reg) {
        int tt = tm0 + quad * 4 + reg;
        float cum = expf(Ahd * SDs[tt]);
#pragma unroll
        for (int j = 0; j < 4; ++j) {
            int dd = j * 16 + fr;
            size_t off = (size_t)(m0 + tt) * D_INNER + xcol + dd;
            yscan[off] += cum * ya[j][reg];
        }
    }
}

// ---------------------------------------------------------------------------
// y = (yscan + D*x) * silu(z); RMSNorm; emits bf16 hi/lo split. xh is bf16.
// ---------------------------------------------------------------------------
__global__ __launch_bounds__(256) void gate_norm_kernel(const float* __restrict__ zx,
                                                        const u16* __restrict__ xh,
                                                        const float* __restrict__ Dp,
                                                        const float* __restrict__ nw,
                                                        const float* __restrict__ y,
                                                        u16* __restrict__ ybf_h,
                                                        u16* __restrict__ ybf_l) {
    const int m = blockIdx.x;
    const int t = threadIdx.x;
    const size_t rowz = (size_t)m * NPROJ;
    const size_t rowy = (size_t)m * D_INNER;

    float v[8];
    float ss = 0.f;
#pragma unroll
    for (int i = 0; i < 8; ++i) {
        int c = t + i * 256;
        float ys = fmaf(Dp[c >> 8], bf2f(xh[rowy + c]), y[rowy + c]);
        float z  = zx[rowz + OFF_Z + c];
        float gated = ys * (z / (1.f + expf(-z)));
        v[i] = gated;
        ss += gated * gated;
    }
#pragma unroll
    for (int off = 1; off < 64; off <<= 1) ss += __shfl_xor(ss, off);

    __shared__ float red[4];
    if ((t & 63) == 0) red[t >> 6] = ss;
    __syncthreads();
    float tot = red[0] + red[1] + red[2] + red[3];
    float scale = 1.f / sqrtf(tot / (float)D_INNER + 1e-6f);

#pragma unroll
    for (int i = 0; i < 8; ++i) {
        int c = t + i * 256;
        float o = v[i] * scale * nw[c];
        u16 h = f2bf(o);
        ybf_h[rowy + c] = h;
        ybf_l[rowy + c] = f2bf(o - bf2f(h));
    }
}

// ---------------------------------------------------------------------------
extern "C" void kernel_launch(void* const* d_in, const int* in_sizes, int n_in,
                              void* d_out, int out_size, void* d_ws, size_t ws_size,
                              hipStream_t stream) {
    const float* x         = (const float*)d_in[0];
    const float* in_proj_w = (const float*)d_in[1];
    const float* conv_w    = (const float*)d_in[2];
    const float* conv_b    = (const float*)d_in[3];
    const float* A_log     = (const float*)d_in[4];
    const float* D_param   = (const float*)d_in[5];
    const float* dt_bias   = (const float*)d_in[6];
    const float* norm_w    = (const float*)d_in[7];
    const float* out_proj_w= (const float*)d_in[8];
    float* out = (float*)d_out;

    // workspace layout (floats), total 76.96 MB:
    //  zx  @0         8,667,136  | later pbuf (2x 2,097,152*2... fits)
    //  R1  @8667136   2,166,784  | wibf_l -> xh(u16) -> wobf h+l
    //  R2  @10833920  4,194,304  | xbf h+l -> ysc
    //  ab  @15028224     16,384
    //  R3  @15044608  4,194,304  | wibf_h -> Sloc -> ybf h+l
    float* ws  = (float*)d_ws;
    float* zx  = ws;
    float* R1  = zx + 8667136;
    float* R2  = R1 + 2166784;
    float* ab  = R2 + 4194304;
    float* R3  = ab + 16384;

    u16*  wibf_l = (u16*)R1;
    u16*  xh     = (u16*)R1;
    u16*  wobf_h = (u16*)R1;
    u16*  wobf_l = wobf_h + (size_t)DIM * D_INNER;      // 2,097,152 each
    u16*  xbf_h  = (u16*)R2;
    u16*  xbf_l  = xbf_h + (size_t)M_ROWS * DIM;
    float* ysc   = R2;
    u16*  wibf_h = (u16*)R3;
    float* Sloc  = R3;
    u16*  ybf_h  = (u16*)R3;
    u16*  ybf_l  = ybf_h + (size_t)M_ROWS * D_INNER;
    float* pbuf  = zx;

    // 0) split casts for GEMM1 (x + in_proj_w, unpadded)
    {
        int n0 = M_ROWS * DIM;              // 2,097,152
        int n1 = NPROJ * DIM;               // 4,333,568
        cast_split2_kernel<<<(n0 + n1) / 1024, 256, 0, stream>>>(
            x, xbf_h, xbf_l, n0, in_proj_w, wibf_h, wibf_l, n1);
    }

    // 1) zxBCdt = x @ in_proj_w^T  (2048 x 4232, K=1024)
    gemm_mfma3<128><<<dim3(NPROJ_PAD / 128, M_ROWS / 128, 1), 256, 0, stream>>>(
        xbf_h, xbf_l, wibf_h, wibf_l, zx, DIM, NPROJ, NPROJ, NPROJ, 0);

    // 2) conv + silu -> xh (bf16) + dt/a_bar -> ab
    conv_silu_kernel<<<(M_ROWS * D_INNER) / 256, 256, 0, stream>>>(
        zx, conv_w, conv_b, dt_bias, A_log, xh, ab);

    // 3) SSD chunked scan (MFMA passes 1 and 3)
    scan_local_mfma<<<BATCH * N_HEADS * N_CHUNK * 4, 256, 0, stream>>>(
        zx, xh, dt_bias, A_log, ysc, Sloc);
    scan_combine_kernel<<<BATCH * N_HEADS * 16, 256, 0, stream>>>(ab, Sloc);
    scan_corr_mfma<<<BATCH * N_HEADS * N_CHUNK * 4, 256, 0, stream>>>(
        zx, dt_bias, A_log, Sloc, ysc);

    // 4) gate + rmsnorm, emits split-bf16 y
    gate_norm_kernel<<<M_ROWS, 256, 0, stream>>>(
        zx, xh, D_param, norm_w, ysc, ybf_h, ybf_l);

    // 5) split cast for GEMM2 weights
    cast_split_kernel<<<(DIM * D_INNER) / 1024, 256, 0, stream>>>(
        out_proj_w, wobf_h, wobf_l, DIM * D_INNER);

    // 6) out = y @ out_proj_w^T  (2048 x 1024, K=2048), BN=64, split-K=2
    gemm_mfma3<64><<<dim3(DIM / 64, M_ROWS / 128, 2), 256, 0, stream>>>(
        ybf_h, ybf_l, wobf_h, wobf_l, pbuf, D_INNER, DIM, DIM, DIM,
        (size_t)M_ROWS * DIM);

    // 7) reduce partials -> out
    reduce2_kernel<<<(M_ROWS * DIM) / 1024, 256, 0, stream>>>(pbuf, out, M_ROWS * DIM);
}